// Round 1
// baseline (49.193 us; speedup 1.0000x reference)
//
#include <hip/hip_runtime.h>

#define ALPHA 0.2f
#define N_ROWS 8192
#define N_FEAT 256

// Kernel 1: per-row dual dot product. One wave (64 lanes) per row,
// each lane loads one float4 (16B) of the row -> 64*4 = 256 features.
__global__ void __launch_bounds__(256) attn_dots(const float* __restrict__ X,
                                                 const float* __restrict__ av,
                                                 float* __restrict__ s) {
    const int wave = threadIdx.x >> 6;
    const int lane = threadIdx.x & 63;
    const int row  = blockIdx.x * 4 + wave;

    const float4* xr   = reinterpret_cast<const float4*>(X + (size_t)row * N_FEAT);
    const float4* asrc = reinterpret_cast<const float4*>(av);
    const float4* adst = reinterpret_cast<const float4*>(av + N_FEAT);

    float4 x  = xr[lane];
    float4 as = asrc[lane];
    float4 ad = adst[lane];

    float ds = x.x * as.x + x.y * as.y + x.z * as.z + x.w * as.w;
    float dd = x.x * ad.x + x.y * ad.y + x.z * ad.z + x.w * ad.w;

    #pragma unroll
    for (int off = 32; off > 0; off >>= 1) {
        ds += __shfl_down(ds, off, 64);
        dd += __shfl_down(dd, off, 64);
    }
    if (lane == 0) {
        s[row]          = ds;   // s_src
        s[N_ROWS + row] = dd;   // s_dst
    }
}

// Kernel 2: out[i][j] = leaky_relu(s_src[i] + s_dst[j]).
// 2048 blocks x 256 threads. Block b owns rows [4b, 4b+4) x all 8192 cols.
// Each thread caches its 8 s_dst float4s in registers (covering the full
// row width across the 256 threads), then streams 32 float4 stores.
// leaky_relu(u) = max(u, ALPHA*u) since 0 < ALPHA < 1  -> 2 VALU ops/elem.
__global__ void __launch_bounds__(256) attn_bcast(const float* __restrict__ s,
                                                  float* __restrict__ out) {
    const int row0 = blockIdx.x << 2;           // first of 4 rows
    const int t    = threadIdx.x;

    const float4* sd4 = reinterpret_cast<const float4*>(s + N_ROWS);
    float4*       o4  = reinterpret_cast<float4*>(out);

    // Load this thread's 8 column chunks of s_dst once (32 KB/block from L2,
    // reused for 4 rows = 128 KB of output).
    float4 sd[8];
    #pragma unroll
    for (int c = 0; c < 8; ++c)
        sd[c] = sd4[c * 256 + t];

    #pragma unroll
    for (int r = 0; r < 4; ++r) {
        const float  ss   = s[row0 + r];                     // block-uniform -> s_load
        const size_t base = (size_t)(row0 + r) * (N_ROWS / 4);
        #pragma unroll
        for (int c = 0; c < 8; ++c) {
            float4 v;
            float  u;
            u = ss + sd[c].x; v.x = fmaxf(u, ALPHA * u);
            u = ss + sd[c].y; v.y = fmaxf(u, ALPHA * u);
            u = ss + sd[c].z; v.z = fmaxf(u, ALPHA * u);
            u = ss + sd[c].w; v.w = fmaxf(u, ALPHA * u);
            o4[base + c * 256 + t] = v;
        }
    }
}

extern "C" void kernel_launch(void* const* d_in, const int* in_sizes, int n_in,
                              void* d_out, int out_size, void* d_ws, size_t ws_size,
                              hipStream_t stream) {
    const float* X  = (const float*)d_in[0];   // feature_matrix [8192, 256]
    const float* av = (const float*)d_in[1];   // attention_vector [512, 1]
    float* out = (float*)d_out;                // [8192, 8192]
    float* s   = (float*)d_ws;                 // [2 * 8192] scratch

    // Kernel 1: 8192 rows / 4 rows-per-block = 2048 blocks of 256 threads.
    attn_dots<<<dim3(N_ROWS / 4), dim3(256), 0, stream>>>(X, av, s);

    // Kernel 2: 2048 blocks of 256 threads, 4 rows per block.
    attn_bcast<<<dim3(N_ROWS / 4), dim3(256), 0, stream>>>(s, out);
}